// Round 1
// baseline (290.140 us; speedup 1.0000x reference)
//
#include <hip/hip_runtime.h>
#include <cstdint>
#include <cstddef>

typedef __attribute__((ext_vector_type(8))) __bf16 bf16x8;
typedef __attribute__((ext_vector_type(4))) __bf16 bf16x4;
typedef __attribute__((ext_vector_type(4))) float f32x4;

#define AS1 __attribute__((address_space(1)))
#define AS3 __attribute__((address_space(3)))

// async global->LDS, 16B per lane; lds must be wave-uniform base (HW does +lane*16)
__device__ __forceinline__ void gld16(void* lds_uniform, const void* gaddr) {
  __builtin_amdgcn_global_load_lds((const AS1 unsigned int*)gaddr,
                                   (AS3 unsigned int*)lds_uniform, 16, 0, 0);
}

// ---------------------------------------------------------------- fp32->bf16
__global__ void cvt_kernel(const float* __restrict__ src, __bf16* __restrict__ dst, int n) {
  int i = (blockIdx.x * 256 + threadIdx.x) * 4;
  if (i < n) {
    const float4 v = *(const float4*)(src + i);
    bf16x4 o;
    o[0] = (__bf16)v.x; o[1] = (__bf16)v.y; o[2] = (__bf16)v.z; o[3] = (__bf16)v.w;
    *(bf16x4*)(dst + i) = o;
  }
}

// ---------------------------------------------------------------- QKV GEMM
// C[m, n] = sum_k x[m,k] * w_qkv[n,k] + bias(n); fused L2-norm epilogue.
// m in [0,4096) = b*2048+l ; n in [0,3072) = which*1024 + h*64 + hd
__global__ __launch_bounds__(256, 2)
void gemm_qkv_kernel(const __bf16* __restrict__ A, const __bf16* __restrict__ B,
                     const float* __restrict__ q_bias, const float* __restrict__ v_bias,
                     const float* __restrict__ scale_mul,
                     __bf16* __restrict__ qb, __bf16* __restrict__ kb, __bf16* __restrict__ vb) {
  __shared__ __attribute__((aligned(16))) __bf16 As[128 * 32];
  __shared__ __attribute__((aligned(16))) __bf16 Bs[128 * 32];
  const int tid = threadIdx.x;
  const int w = tid >> 6, lane = tid & 63;
  const int m0 = blockIdx.y * 128, n0 = blockIdx.x * 128;
  const int wm = (w >> 1) * 64, wn = (w & 1) * 64;
  f32x4 acc[4][4];
#pragma unroll
  for (int i = 0; i < 4; ++i)
#pragma unroll
    for (int j = 0; j < 4; ++j) acc[i][j] = (f32x4)(0.0f);

  const int r_row = lane >> 2;
  const int r_col = (lane & 3) * 16;
  const char* Abase = (const char*)A + (size_t)m0 * 2048;
  const char* Bbase = (const char*)B + (size_t)n0 * 2048;

  for (int kt = 0; kt < 1024; kt += 32) {
#pragma unroll
    for (int s = 0; s < 2; ++s) {
      const int R = w * 2 + s;
      const int row = R * 16 + r_row;
      gld16((char*)As + R * 1024, Abase + (size_t)row * 2048 + kt * 2 + r_col);
      gld16((char*)Bs + R * 1024, Bbase + (size_t)row * 2048 + kt * 2 + r_col);
    }
    __syncthreads();
    bf16x8 af[4], bfr[4];
#pragma unroll
    for (int i = 0; i < 4; ++i) {
      af[i]  = *(const bf16x8*)((const char*)As + (wm + i * 16 + (lane & 15)) * 64 + (lane >> 4) * 16);
      bfr[i] = *(const bf16x8*)((const char*)Bs + (wn + i * 16 + (lane & 15)) * 64 + (lane >> 4) * 16);
    }
#pragma unroll
    for (int mi = 0; mi < 4; ++mi)
#pragma unroll
      for (int ni = 0; ni < 4; ++ni)
        acc[mi][ni] = __builtin_amdgcn_mfma_f32_16x16x32_bf16(af[mi], bfr[ni], acc[mi][ni], 0, 0, 0);
    __syncthreads();
  }

  // epilogue: bias add, per-row L2 norm over the wave's 64 cols (= one head), bf16 scatter
  const int nbase = n0 + wn;            // 64-aligned -> single (which, h) per wave
  const int which = nbase >> 10;
  const int h = (nbase >> 6) & 15;
  float smh = 1.0f;
  if (which == 0) smh = __expf(fminf(scale_mul[h], 4.605170185988091f));
  float cbias[4];
#pragma unroll
  for (int ni = 0; ni < 4; ++ni) {
    const int n = nbase + ni * 16 + (lane & 15);
    cbias[ni] = (which == 0) ? q_bias[n] : ((which == 2) ? v_bias[n - 2048] : 0.0f);
  }
  __bf16* dst = (which == 0) ? qb : ((which == 1) ? kb : vb);
#pragma unroll
  for (int mi = 0; mi < 4; ++mi) {
#pragma unroll
    for (int j = 0; j < 4; ++j) {
      const int m = m0 + wm + mi * 16 + (lane >> 4) * 4 + j;
      float v[4];
      float ss = 0.0f;
#pragma unroll
      for (int ni = 0; ni < 4; ++ni) { v[ni] = acc[mi][ni][j] + cbias[ni]; ss += v[ni] * v[ni]; }
      ss += __shfl_xor(ss, 1, 64);
      ss += __shfl_xor(ss, 2, 64);
      ss += __shfl_xor(ss, 4, 64);
      ss += __shfl_xor(ss, 8, 64);
      const float sc = (which == 2) ? 1.0f : (rsqrtf(ss) * smh);
      const int b2 = m >> 11, lpos = m & 2047;
      __bf16* drow = dst + ((size_t)((b2 * 16 + h) * 2048 + lpos)) * 64;
#pragma unroll
      for (int ni = 0; ni < 4; ++ni)
        drow[ni * 16 + (lane & 15)] = (__bf16)(v[ni] * sc);
    }
  }
}

// ---------------------------------------------------------------- flash attention (bf16 MFMA)
// grid: blockIdx.x = qt*32 + bh  (bh fastest -> 32 consecutive blocks share a bias slab)
__global__ __launch_bounds__(256, 2)
void attn_kernel(const __bf16* __restrict__ qb, const __bf16* __restrict__ kb,
                 const __bf16* __restrict__ vb, const __bf16* __restrict__ biasb,
                 __bf16* __restrict__ oupb) {
  __shared__ __attribute__((aligned(16))) __bf16 Ks[2 * 64 * 32]; // byte = ks*4096 + key*64 + hd2*2
  __shared__ __attribute__((aligned(16))) __bf16 Vt[64][72];      // [hd][key], pad 8
  __shared__ __attribute__((aligned(16))) __bf16 Ps[4][32][72];   // per-wave P, [row][key], pad 8
  const int tid = threadIdx.x;
  const int w = tid >> 6, lane = tid & 63;
  const int bh = blockIdx.x & 31, qt = blockIdx.x >> 5;
  const int b2 = bh >> 4, h = bh & 15;
  const __bf16* qh = qb + (size_t)bh * (2048 * 64);
  const __bf16* kh = kb + (size_t)bh * (2048 * 64);
  const __bf16* vh = vb + (size_t)bh * (2048 * 64);
  const int q0 = qt * 128 + w * 32;

  bf16x8 qf[2][2];
#pragma unroll
  for (int mi = 0; mi < 2; ++mi)
#pragma unroll
    for (int ks = 0; ks < 2; ++ks)
      qf[mi][ks] = *(const bf16x8*)(qh + (size_t)(q0 + mi * 16 + (lane & 15)) * 64 + ks * 32 + (lane >> 4) * 8);

  f32x4 oacc[2][4];
  float mrun[2][4], lrun[2][4];
#pragma unroll
  for (int mi = 0; mi < 2; ++mi)
#pragma unroll
    for (int j = 0; j < 4; ++j) { mrun[mi][j] = -1e30f; lrun[mi][j] = 0.0f; }
#pragma unroll
  for (int mi = 0; mi < 2; ++mi)
#pragma unroll
    for (int ni = 0; ni < 4; ++ni) oacc[mi][ni] = (f32x4)(0.0f);

  for (int kt = 0; kt < 2048; kt += 64) {
    __syncthreads();  // protect Ks/Vt from prior iteration readers
    // K tile: async copy into split-[ks][key][32] layout (keeps 64B row stride)
#pragma unroll
    for (int s = 0; s < 2; ++s) {
      const int R = w * 2 + s;
      const int o = R * 1024 + lane * 16;
      const int ks = o >> 12, key = (o >> 6) & 63, ib = o & 63;
      gld16((char*)Ks + R * 1024, (const char*)kh + (size_t)(kt + key) * 128 + ks * 64 + ib);
    }
    // V tile transposed: wave w handles hd chunk [w*16, w*16+16), key = lane
    {
      const __bf16* vsrc = vh + (size_t)(kt + lane) * 64 + w * 16;
      bf16x8 v0 = *(const bf16x8*)(vsrc);
      bf16x8 v1 = *(const bf16x8*)(vsrc + 8);
#pragma unroll
      for (int j = 0; j < 8; ++j) Vt[w * 16 + j][lane] = v0[j];
#pragma unroll
      for (int j = 0; j < 8; ++j) Vt[w * 16 + 8 + j][lane] = v1[j];
    }
    // bias prefetch (bf16 scalars), overlaps staging
    float bias_r[2][4][4];
#pragma unroll
    for (int mi = 0; mi < 2; ++mi)
#pragma unroll
      for (int j = 0; j < 4; ++j) {
        const size_t brow = (size_t)(q0 + mi * 16 + (lane >> 4) * 4 + j) * 2048;
#pragma unroll
        for (int ni = 0; ni < 4; ++ni)
          bias_r[mi][ni][j] = (float)biasb[brow + kt + ni * 16 + (lane & 15)];
      }
    __syncthreads();  // drains vmcnt -> K staged; lgkm -> Vt written

    // S = Q K^T
    bf16x8 kf[4][2];
#pragma unroll
    for (int ni = 0; ni < 4; ++ni)
#pragma unroll
      for (int ks = 0; ks < 2; ++ks)
        kf[ni][ks] = *(const bf16x8*)((const char*)Ks + ks * 4096 + (ni * 16 + (lane & 15)) * 64 + (lane >> 4) * 16);
    f32x4 sacc[2][4];
#pragma unroll
    for (int mi = 0; mi < 2; ++mi)
#pragma unroll
      for (int ni = 0; ni < 4; ++ni) {
        f32x4 c = (f32x4)(0.0f);
        c = __builtin_amdgcn_mfma_f32_16x16x32_bf16(qf[mi][0], kf[ni][0], c, 0, 0, 0);
        c = __builtin_amdgcn_mfma_f32_16x16x32_bf16(qf[mi][1], kf[ni][1], c, 0, 0, 0);
        sacc[mi][ni] = c;
      }

    // online softmax (C-layout: row = (lane>>4)*4+j, col = lane&15)
#pragma unroll
    for (int mi = 0; mi < 2; ++mi) {
#pragma unroll
      for (int j = 0; j < 4; ++j) {
        float s0 = sacc[mi][0][j] + bias_r[mi][0][j];
        float s1 = sacc[mi][1][j] + bias_r[mi][1][j];
        float s2 = sacc[mi][2][j] + bias_r[mi][2][j];
        float s3 = sacc[mi][3][j] + bias_r[mi][3][j];
        float tm = fmaxf(fmaxf(s0, s1), fmaxf(s2, s3));
        tm = fmaxf(tm, __shfl_xor(tm, 1, 64));
        tm = fmaxf(tm, __shfl_xor(tm, 2, 64));
        tm = fmaxf(tm, __shfl_xor(tm, 4, 64));
        tm = fmaxf(tm, __shfl_xor(tm, 8, 64));
        const float mnew = fmaxf(mrun[mi][j], tm);
        const float alpha = __expf(mrun[mi][j] - mnew);
        mrun[mi][j] = mnew;
        const float p0 = __expf(s0 - mnew), p1 = __expf(s1 - mnew);
        const float p2 = __expf(s2 - mnew), p3 = __expf(s3 - mnew);
        float ts = p0 + p1 + p2 + p3;
        ts += __shfl_xor(ts, 1, 64);
        ts += __shfl_xor(ts, 2, 64);
        ts += __shfl_xor(ts, 4, 64);
        ts += __shfl_xor(ts, 8, 64);
        lrun[mi][j] = lrun[mi][j] * alpha + ts;
        const int prow = mi * 16 + (lane >> 4) * 4 + j;
        Ps[w][prow][0 + (lane & 15)]  = (__bf16)p0;
        Ps[w][prow][16 + (lane & 15)] = (__bf16)p1;
        Ps[w][prow][32 + (lane & 15)] = (__bf16)p2;
        Ps[w][prow][48 + (lane & 15)] = (__bf16)p3;
#pragma unroll
        for (int ni = 0; ni < 4; ++ni) oacc[mi][ni][j] *= alpha;
      }
    }

    // O += P V  (P via per-wave LDS round-trip into A-layout; no barrier needed, same-wave)
    bf16x8 pf[2][2], vf[4][2];
#pragma unroll
    for (int mi = 0; mi < 2; ++mi)
#pragma unroll
      for (int ks = 0; ks < 2; ++ks)
        pf[mi][ks] = *(const bf16x8*)((const char*)&Ps[w][0][0] + (mi * 16 + (lane & 15)) * 144 + ks * 64 + (lane >> 4) * 16);
#pragma unroll
    for (int ni = 0; ni < 4; ++ni)
#pragma unroll
      for (int ks = 0; ks < 2; ++ks)
        vf[ni][ks] = *(const bf16x8*)((const char*)&Vt[0][0] + (ni * 16 + (lane & 15)) * 144 + ks * 64 + (lane >> 4) * 16);
#pragma unroll
    for (int mi = 0; mi < 2; ++mi)
#pragma unroll
      for (int ni = 0; ni < 4; ++ni) {
        oacc[mi][ni] = __builtin_amdgcn_mfma_f32_16x16x32_bf16(pf[mi][0], vf[ni][0], oacc[mi][ni], 0, 0, 0);
        oacc[mi][ni] = __builtin_amdgcn_mfma_f32_16x16x32_bf16(pf[mi][1], vf[ni][1], oacc[mi][ni], 0, 0, 0);
      }
  }

  // normalize by l and write in [B, L, H*HD] layout (= proj A matrix)
#pragma unroll
  for (int mi = 0; mi < 2; ++mi)
#pragma unroll
    for (int j = 0; j < 4; ++j) {
      const float inv = 1.0f / lrun[mi][j];
      const int qrow = q0 + mi * 16 + (lane >> 4) * 4 + j;
      __bf16* orow = oupb + ((size_t)(b2 * 2048 + qrow) * 16 + h) * 64;
#pragma unroll
      for (int ni = 0; ni < 4; ++ni)
        orow[ni * 16 + (lane & 15)] = (__bf16)(oacc[mi][ni][j] * inv);
    }
}

// ---------------------------------------------------------------- proj GEMM
__global__ __launch_bounds__(256, 2)
void gemm_proj_kernel(const __bf16* __restrict__ A, const __bf16* __restrict__ B,
                      const float* __restrict__ b_proj, float* __restrict__ out) {
  __shared__ __attribute__((aligned(16))) __bf16 As[128 * 32];
  __shared__ __attribute__((aligned(16))) __bf16 Bs[128 * 32];
  const int tid = threadIdx.x;
  const int w = tid >> 6, lane = tid & 63;
  const int m0 = blockIdx.y * 128, n0 = blockIdx.x * 128;
  const int wm = (w >> 1) * 64, wn = (w & 1) * 64;
  f32x4 acc[4][4];
#pragma unroll
  for (int i = 0; i < 4; ++i)
#pragma unroll
    for (int j = 0; j < 4; ++j) acc[i][j] = (f32x4)(0.0f);

  const int r_row = lane >> 2;
  const int r_col = (lane & 3) * 16;
  const char* Abase = (const char*)A + (size_t)m0 * 2048;
  const char* Bbase = (const char*)B + (size_t)n0 * 2048;

  for (int kt = 0; kt < 1024; kt += 32) {
#pragma unroll
    for (int s = 0; s < 2; ++s) {
      const int R = w * 2 + s;
      const int row = R * 16 + r_row;
      gld16((char*)As + R * 1024, Abase + (size_t)row * 2048 + kt * 2 + r_col);
      gld16((char*)Bs + R * 1024, Bbase + (size_t)row * 2048 + kt * 2 + r_col);
    }
    __syncthreads();
    bf16x8 af[4], bfr[4];
#pragma unroll
    for (int i = 0; i < 4; ++i) {
      af[i]  = *(const bf16x8*)((const char*)As + (wm + i * 16 + (lane & 15)) * 64 + (lane >> 4) * 16);
      bfr[i] = *(const bf16x8*)((const char*)Bs + (wn + i * 16 + (lane & 15)) * 64 + (lane >> 4) * 16);
    }
#pragma unroll
    for (int mi = 0; mi < 4; ++mi)
#pragma unroll
      for (int ni = 0; ni < 4; ++ni)
        acc[mi][ni] = __builtin_amdgcn_mfma_f32_16x16x32_bf16(af[mi], bfr[ni], acc[mi][ni], 0, 0, 0);
    __syncthreads();
  }

  float cbias[4];
#pragma unroll
  for (int ni = 0; ni < 4; ++ni) cbias[ni] = b_proj[n0 + wn + ni * 16 + (lane & 15)];
#pragma unroll
  for (int mi = 0; mi < 4; ++mi)
#pragma unroll
    for (int j = 0; j < 4; ++j) {
      const int m = m0 + wm + mi * 16 + (lane >> 4) * 4 + j;
      float* orow = out + (size_t)m * 1024 + n0 + wn;
#pragma unroll
      for (int ni = 0; ni < 4; ++ni)
        orow[ni * 16 + (lane & 15)] = acc[mi][ni][j] + cbias[ni];
    }
}

// ---------------------------------------------------------------- launch
extern "C" void kernel_launch(void* const* d_in, const int* in_sizes, int n_in,
                              void* d_out, int out_size, void* d_ws, size_t ws_size,
                              hipStream_t stream) {
  const float* x         = (const float*)d_in[0];  // [2,2048,1024]
  const float* attn_bias = (const float*)d_in[1];  // [1,1,2048,2048]
  const float* w_qkv     = (const float*)d_in[2];  // [3072,1024]
  const float* q_bias    = (const float*)d_in[3];  // [1024]
  const float* v_bias    = (const float*)d_in[4];  // [1024]
  const float* scale_mul = (const float*)d_in[5];  // [16]
  const float* w_proj    = (const float*)d_in[6];  // [1024,1024]
  const float* b_proj    = (const float*)d_in[7];  // [1024]
  float* out = (float*)d_out;

  __bf16* xb     = (__bf16*)d_ws;                 // 4096*1024
  __bf16* wqkvb  = xb + 4096 * 1024;              // 3072*1024
  __bf16* wprojb = wqkvb + 3072 * 1024;           // 1024*1024
  __bf16* biasb  = wprojb + 1024 * 1024;          // 2048*2048
  __bf16* qb     = biasb + 2048 * 2048;           // 2*16*2048*64
  __bf16* kb     = qb + 2 * 16 * 2048 * 64;
  __bf16* vb     = kb + 2 * 16 * 2048 * 64;
  __bf16* oupb   = vb + 2 * 16 * 2048 * 64;       // 4096*1024

  cvt_kernel<<<4096, 256, 0, stream>>>(x, xb, 4096 * 1024);
  cvt_kernel<<<3072, 256, 0, stream>>>(w_qkv, wqkvb, 3072 * 1024);
  cvt_kernel<<<1024, 256, 0, stream>>>(w_proj, wprojb, 1024 * 1024);
  cvt_kernel<<<4096, 256, 0, stream>>>(attn_bias, biasb, 2048 * 2048);

  gemm_qkv_kernel<<<dim3(24, 32), 256, 0, stream>>>(xb, wqkvb, q_bias, v_bias, scale_mul,
                                                    qb, kb, vb);
  attn_kernel<<<512, 256, 0, stream>>>(qb, kb, vb, biasb, oupb);
  gemm_proj_kernel<<<dim3(8, 32), 256, 0, stream>>>(oupb, wprojb, b_proj, out);
}

// Round 2
// 255.463 us; speedup vs baseline: 1.1357x; 1.1357x over previous
//
#include <hip/hip_runtime.h>
#include <cstdint>
#include <cstddef>
#include <math.h>

typedef __attribute__((ext_vector_type(8))) __bf16 bf16x8;
typedef __attribute__((ext_vector_type(4))) __bf16 bf16x4;
typedef __attribute__((ext_vector_type(4))) float f32x4;

#define AS1 __attribute__((address_space(1)))
#define AS3 __attribute__((address_space(3)))

#define LOG2E 1.4426950408889634f

// async global->LDS, 16B per lane; lds must be wave-uniform base (HW does +lane*16)
__device__ __forceinline__ void gld16(void* lds_uniform, const void* gaddr) {
  __builtin_amdgcn_global_load_lds((const AS1 unsigned int*)gaddr,
                                   (AS3 unsigned int*)lds_uniform, 16, 0, 0);
}

// ---------------------------------------------------------------- fp32->bf16 (with scale)
__global__ void cvt_kernel(const float* __restrict__ src, __bf16* __restrict__ dst, int n,
                           float scale) {
  int i = (blockIdx.x * 256 + threadIdx.x) * 4;
  if (i < n) {
    const float4 v = *(const float4*)(src + i);
    bf16x4 o;
    o[0] = (__bf16)(v.x * scale); o[1] = (__bf16)(v.y * scale);
    o[2] = (__bf16)(v.z * scale); o[3] = (__bf16)(v.w * scale);
    *(bf16x4*)(dst + i) = o;
  }
}

// ---------------------------------------------------------------- QKV GEMM
// C[m, n] = sum_k x[m,k] * w_qkv[n,k] + bias(n); fused L2-norm epilogue.
// q additionally scaled by log2e (folded into softmax exp2).
__global__ __launch_bounds__(256, 2)
void gemm_qkv_kernel(const __bf16* __restrict__ A, const __bf16* __restrict__ B,
                     const float* __restrict__ q_bias, const float* __restrict__ v_bias,
                     const float* __restrict__ scale_mul,
                     __bf16* __restrict__ qb, __bf16* __restrict__ kb, __bf16* __restrict__ vb) {
  __shared__ __attribute__((aligned(16))) __bf16 As[128 * 32];
  __shared__ __attribute__((aligned(16))) __bf16 Bs[128 * 32];
  const int tid = threadIdx.x;
  const int w = tid >> 6, lane = tid & 63;
  const int m0 = blockIdx.y * 128, n0 = blockIdx.x * 128;
  const int wm = (w >> 1) * 64, wn = (w & 1) * 64;
  f32x4 acc[4][4];
#pragma unroll
  for (int i = 0; i < 4; ++i)
#pragma unroll
    for (int j = 0; j < 4; ++j) acc[i][j] = (f32x4)(0.0f);

  const int r_row = lane >> 2;
  const int r_col = (lane & 3) * 16;
  const char* Abase = (const char*)A + (size_t)m0 * 2048;
  const char* Bbase = (const char*)B + (size_t)n0 * 2048;

  for (int kt = 0; kt < 1024; kt += 32) {
#pragma unroll
    for (int s = 0; s < 2; ++s) {
      const int R = w * 2 + s;
      const int row = R * 16 + r_row;
      gld16((char*)As + R * 1024, Abase + (size_t)row * 2048 + kt * 2 + r_col);
      gld16((char*)Bs + R * 1024, Bbase + (size_t)row * 2048 + kt * 2 + r_col);
    }
    __syncthreads();
    bf16x8 af[4], bfr[4];
#pragma unroll
    for (int i = 0; i < 4; ++i) {
      af[i]  = *(const bf16x8*)((const char*)As + (wm + i * 16 + (lane & 15)) * 64 + (lane >> 4) * 16);
      bfr[i] = *(const bf16x8*)((const char*)Bs + (wn + i * 16 + (lane & 15)) * 64 + (lane >> 4) * 16);
    }
#pragma unroll
    for (int mi = 0; mi < 4; ++mi)
#pragma unroll
      for (int ni = 0; ni < 4; ++ni)
        acc[mi][ni] = __builtin_amdgcn_mfma_f32_16x16x32_bf16(af[mi], bfr[ni], acc[mi][ni], 0, 0, 0);
    __syncthreads();
  }

  const int nbase = n0 + wn;            // 64-aligned -> single (which, h) per wave
  const int which = nbase >> 10;
  const int h = (nbase >> 6) & 15;
  float smh = 1.0f;
  if (which == 0) smh = __expf(fminf(scale_mul[h], 4.605170185988091f)) * LOG2E;
  float cbias[4];
#pragma unroll
  for (int ni = 0; ni < 4; ++ni) {
    const int n = nbase + ni * 16 + (lane & 15);
    cbias[ni] = (which == 0) ? q_bias[n] : ((which == 2) ? v_bias[n - 2048] : 0.0f);
  }
  __bf16* dst = (which == 0) ? qb : ((which == 1) ? kb : vb);
#pragma unroll
  for (int mi = 0; mi < 4; ++mi) {
#pragma unroll
    for (int j = 0; j < 4; ++j) {
      const int m = m0 + wm + mi * 16 + (lane >> 4) * 4 + j;
      float v[4];
      float ss = 0.0f;
#pragma unroll
      for (int ni = 0; ni < 4; ++ni) { v[ni] = acc[mi][ni][j] + cbias[ni]; ss += v[ni] * v[ni]; }
      ss += __shfl_xor(ss, 1, 64);
      ss += __shfl_xor(ss, 2, 64);
      ss += __shfl_xor(ss, 4, 64);
      ss += __shfl_xor(ss, 8, 64);
      const float sc = (which == 2) ? 1.0f : (rsqrtf(ss) * smh);
      const int b2 = m >> 11, lpos = m & 2047;
      __bf16* drow = dst + ((size_t)((b2 * 16 + h) * 2048 + lpos)) * 64;
#pragma unroll
      for (int ni = 0; ni < 4; ++ni)
        drow[ni * 16 + (lane & 15)] = (__bf16)(v[ni] * sc);
    }
  }
}

// ---------------------------------------------------------------- V transpose to tile-slot layout
// vb [bh][2048][64] -> vtp [bh][tile=32][4096] where tile elem (ks*2048 + hd*32 + s32)
//   = V[key][hd], key = tile*64 + (slot&3)*16 + (slot>>2), slot = ks*32+s32.
__global__ __launch_bounds__(256)
void vtrans_kernel(const __bf16* __restrict__ vb, __bf16* __restrict__ vtp) {
  __shared__ __attribute__((aligned(16))) __bf16 Vs[4][64 * 64];
  const int w = threadIdx.x >> 6, lane = threadIdx.x & 63;
  const int idx = blockIdx.x * 4 + w;
  const int bh = idx >> 5, tile = idx & 31;
  const __bf16* src = vb + ((size_t)bh * 2048 + tile * 64) * 64;
#pragma unroll
  for (int s = 0; s < 8; ++s)
    gld16((char*)&Vs[w][0] + s * 1024, (const char*)src + s * 1024 + lane * 16);
  __syncthreads();
  __bf16* outb = vtp + (size_t)idx * 4096;
#pragma unroll
  for (int r = 0; r < 8; ++r) {
    const int o = r * 512 + lane * 8;
    const int hd = (o >> 5) & 63;
    const int sl0 = ((o >> 11) << 5) | (o & 31);   // global slot of first elem
    bf16x8 pk;
#pragma unroll
    for (int i = 0; i < 8; ++i) {
      const int slot = sl0 + i;
      const int key = (slot & 3) * 16 + (slot >> 2);
      pk[i] = Vs[w][key * 64 + hd];
    }
    *(bf16x8*)(outb + o) = pk;
  }
}

// ---------------------------------------------------------------- flash attention (bf16 MFMA)
// 64 q-rows per block (2 waves x 32 rows); fixed-shift-free softmax (no max, no shuffles in loop).
// grid: blockIdx.x = qt*32 + bh
__global__ __launch_bounds__(128, 2)
void attn_kernel(const __bf16* __restrict__ qb, const __bf16* __restrict__ kb,
                 const __bf16* __restrict__ vtp, const __bf16* __restrict__ biasb,
                 __bf16* __restrict__ oupb) {
  __shared__ __attribute__((aligned(16))) __bf16 Ks[2 * 64 * 32];   // [ks][key][32 hd-slots]
  __shared__ __attribute__((aligned(16))) __bf16 Vs[2 * 64 * 32];   // [ks][hd][32 key-slots]
  __shared__ __attribute__((aligned(16))) __bf16 Ps[2][2][32][32];  // [wave][ks][row][slot]
  const int tid = threadIdx.x, w = tid >> 6, lane = tid & 63;
  const int g = lane >> 4, c = lane & 15;
  const int bh = blockIdx.x & 31, qt = blockIdx.x >> 5;
  const int b2 = bh >> 4, h = bh & 15;
  const __bf16* qh = qb + (size_t)bh * (2048 * 64);
  const __bf16* kh = kb + (size_t)bh * (2048 * 64);
  const __bf16* vh = vtp + (size_t)bh * (32 * 4096);
  const int q0 = qt * 64 + w * 32;

  bf16x8 qf[2][2];
#pragma unroll
  for (int mi = 0; mi < 2; ++mi)
#pragma unroll
    for (int ks = 0; ks < 2; ++ks)
      qf[mi][ks] = *(const bf16x8*)(qh + (size_t)(q0 + mi * 16 + c) * 64 + ks * 32 + g * 8);

  f32x4 oacc[2][4];
  float lsum[2][4];
#pragma unroll
  for (int mi = 0; mi < 2; ++mi)
#pragma unroll
    for (int ni = 0; ni < 4; ++ni) oacc[mi][ni] = (f32x4)(0.0f);
#pragma unroll
  for (int mi = 0; mi < 2; ++mi)
#pragma unroll
    for (int j = 0; j < 4; ++j) lsum[mi][j] = 0.0f;

  for (int kt = 0; kt < 2048; kt += 64) {
    __syncthreads();  // previous tile fully consumed
#pragma unroll
    for (int s = 0; s < 4; ++s) {
      const int R = w * 4 + s;
      const int o = R * 1024 + lane * 16;
      const int ks_ = o >> 12, key = (o >> 6) & 63, ib = o & 63;
      gld16((char*)Ks + R * 1024, (const char*)kh + (size_t)(kt + key) * 128 + ks_ * 64 + ib);
      gld16((char*)Vs + R * 1024, (const char*)vh + (size_t)(kt >> 6) * 8192 + R * 1024 + lane * 16);
    }
    // bias (bf16, pre-scaled by log2e) straight from global; overlaps staging
    float br[2][4][4];
#pragma unroll
    for (int mi = 0; mi < 2; ++mi)
#pragma unroll
      for (int j = 0; j < 4; ++j) {
        const __bf16* bp = biasb + (size_t)(q0 + mi * 16 + g * 4 + j) * 2048 + kt + c;
#pragma unroll
        for (int ni = 0; ni < 4; ++ni) br[mi][ni][j] = (float)bp[ni * 16];
      }
    __syncthreads();  // drains vmcnt -> Ks/Vs staged

    bf16x8 kf[4][2];
#pragma unroll
    for (int ni = 0; ni < 4; ++ni)
#pragma unroll
      for (int ks = 0; ks < 2; ++ks)
        kf[ni][ks] = *(const bf16x8*)((const char*)Ks + ks * 4096 + (ni * 16 + c) * 64 + g * 16);

#pragma unroll
    for (int mi = 0; mi < 2; ++mi) {
      f32x4 sc[4];
#pragma unroll
      for (int ni = 0; ni < 4; ++ni) {
        f32x4 s_ = (f32x4)(0.0f);
        s_ = __builtin_amdgcn_mfma_f32_16x16x32_bf16(qf[mi][0], kf[ni][0], s_, 0, 0, 0);
        s_ = __builtin_amdgcn_mfma_f32_16x16x32_bf16(qf[mi][1], kf[ni][1], s_, 0, 0, 0);
        sc[ni] = s_;
      }
#pragma unroll
      for (int j = 0; j < 4; ++j) {
        const float p0 = exp2f(sc[0][j] + br[mi][0][j]);
        const float p1 = exp2f(sc[1][j] + br[mi][1][j]);
        const float p2 = exp2f(sc[2][j] + br[mi][2][j]);
        const float p3 = exp2f(sc[3][j] + br[mi][3][j]);
        lsum[mi][j] += (p0 + p1) + (p2 + p3);
        bf16x4 pk;
        pk[0] = (__bf16)p0; pk[1] = (__bf16)p1; pk[2] = (__bf16)p2; pk[3] = (__bf16)p3;
        *(bf16x4*)&Ps[w][c >> 3][mi * 16 + g * 4 + j][(c & 7) * 4] = pk;
      }
    }

    // O += P V  (same-wave LDS round-trip; lgkmcnt ordering handled by compiler)
    bf16x8 pf[2][2], vf[4][2];
#pragma unroll
    for (int mi = 0; mi < 2; ++mi)
#pragma unroll
      for (int ks = 0; ks < 2; ++ks)
        pf[mi][ks] = *(const bf16x8*)&Ps[w][ks][mi * 16 + c][g * 8];
#pragma unroll
    for (int ni = 0; ni < 4; ++ni)
#pragma unroll
      for (int ks = 0; ks < 2; ++ks)
        vf[ni][ks] = *(const bf16x8*)((const char*)Vs + ks * 4096 + (ni * 16 + c) * 64 + g * 16);
#pragma unroll
    for (int mi = 0; mi < 2; ++mi)
#pragma unroll
      for (int ni = 0; ni < 4; ++ni) {
        oacc[mi][ni] = __builtin_amdgcn_mfma_f32_16x16x32_bf16(pf[mi][0], vf[ni][0], oacc[mi][ni], 0, 0, 0);
        oacc[mi][ni] = __builtin_amdgcn_mfma_f32_16x16x32_bf16(pf[mi][1], vf[ni][1], oacc[mi][ni], 0, 0, 0);
      }
  }

  // deferred row-sum reduce (once) + normalize + write [B, L, H*HD]
#pragma unroll
  for (int mi = 0; mi < 2; ++mi)
#pragma unroll
    for (int j = 0; j < 4; ++j) {
      float l = lsum[mi][j];
      l += __shfl_xor(l, 1, 64);
      l += __shfl_xor(l, 2, 64);
      l += __shfl_xor(l, 4, 64);
      l += __shfl_xor(l, 8, 64);
      const float inv = 1.0f / l;
      const int qrow = q0 + mi * 16 + g * 4 + j;
      __bf16* orow = oupb + ((size_t)(b2 * 2048 + qrow) * 16 + h) * 64;
#pragma unroll
      for (int ni = 0; ni < 4; ++ni)
        orow[ni * 16 + c] = (__bf16)(oacc[mi][ni][j] * inv);
    }
}

// ---------------------------------------------------------------- proj GEMM
__global__ __launch_bounds__(256, 2)
void gemm_proj_kernel(const __bf16* __restrict__ A, const __bf16* __restrict__ B,
                      const float* __restrict__ b_proj, float* __restrict__ out) {
  __shared__ __attribute__((aligned(16))) __bf16 As[128 * 32];
  __shared__ __attribute__((aligned(16))) __bf16 Bs[128 * 32];
  const int tid = threadIdx.x;
  const int w = tid >> 6, lane = tid & 63;
  const int m0 = blockIdx.y * 128, n0 = blockIdx.x * 128;
  const int wm = (w >> 1) * 64, wn = (w & 1) * 64;
  f32x4 acc[4][4];
#pragma unroll
  for (int i = 0; i < 4; ++i)
#pragma unroll
    for (int j = 0; j < 4; ++j) acc[i][j] = (f32x4)(0.0f);

  const int r_row = lane >> 2;
  const int r_col = (lane & 3) * 16;
  const char* Abase = (const char*)A + (size_t)m0 * 2048;
  const char* Bbase = (const char*)B + (size_t)n0 * 2048;

  for (int kt = 0; kt < 1024; kt += 32) {
#pragma unroll
    for (int s = 0; s < 2; ++s) {
      const int R = w * 2 + s;
      const int row = R * 16 + r_row;
      gld16((char*)As + R * 1024, Abase + (size_t)row * 2048 + kt * 2 + r_col);
      gld16((char*)Bs + R * 1024, Bbase + (size_t)row * 2048 + kt * 2 + r_col);
    }
    __syncthreads();
    bf16x8 af[4], bfr[4];
#pragma unroll
    for (int i = 0; i < 4; ++i) {
      af[i]  = *(const bf16x8*)((const char*)As + (wm + i * 16 + (lane & 15)) * 64 + (lane >> 4) * 16);
      bfr[i] = *(const bf16x8*)((const char*)Bs + (wn + i * 16 + (lane & 15)) * 64 + (lane >> 4) * 16);
    }
#pragma unroll
    for (int mi = 0; mi < 4; ++mi)
#pragma unroll
      for (int ni = 0; ni < 4; ++ni)
        acc[mi][ni] = __builtin_amdgcn_mfma_f32_16x16x32_bf16(af[mi], bfr[ni], acc[mi][ni], 0, 0, 0);
    __syncthreads();
  }

  float cbias[4];
#pragma unroll
  for (int ni = 0; ni < 4; ++ni) cbias[ni] = b_proj[n0 + wn + ni * 16 + (lane & 15)];
#pragma unroll
  for (int mi = 0; mi < 4; ++mi)
#pragma unroll
    for (int j = 0; j < 4; ++j) {
      const int m = m0 + wm + mi * 16 + (lane >> 4) * 4 + j;
      float* orow = out + (size_t)m * 1024 + n0 + wn;
#pragma unroll
      for (int ni = 0; ni < 4; ++ni)
        orow[ni * 16 + (lane & 15)] = acc[mi][ni][j] + cbias[ni];
    }
}

// ---------------------------------------------------------------- launch
extern "C" void kernel_launch(void* const* d_in, const int* in_sizes, int n_in,
                              void* d_out, int out_size, void* d_ws, size_t ws_size,
                              hipStream_t stream) {
  const float* x         = (const float*)d_in[0];  // [2,2048,1024]
  const float* attn_bias = (const float*)d_in[1];  // [1,1,2048,2048]
  const float* w_qkv     = (const float*)d_in[2];  // [3072,1024]
  const float* q_bias    = (const float*)d_in[3];  // [1024]
  const float* v_bias    = (const float*)d_in[4];  // [1024]
  const float* scale_mul = (const float*)d_in[5];  // [16]
  const float* w_proj    = (const float*)d_in[6];  // [1024,1024]
  const float* b_proj    = (const float*)d_in[7];  // [1024]
  float* out = (float*)d_out;

  __bf16* xb     = (__bf16*)d_ws;                 // 4096*1024
  __bf16* wqkvb  = xb + 4096 * 1024;              // 3072*1024
  __bf16* wprojb = wqkvb + 3072 * 1024;           // 1024*1024
  __bf16* biasb  = wprojb + 1024 * 1024;          // 2048*2048 (scaled by log2e)
  __bf16* qb     = biasb + 2048 * 2048;           // 2*16*2048*64 (scaled by log2e)
  __bf16* kb     = qb + 2 * 16 * 2048 * 64;
  __bf16* vb     = kb + 2 * 16 * 2048 * 64;
  __bf16* oupb   = vb + 2 * 16 * 2048 * 64;       // 4096*1024
  __bf16* vtp    = oupb + 4096 * 1024;            // 2*16*2048*64 (V transposed, slot layout)

  cvt_kernel<<<4096, 256, 0, stream>>>(x, xb, 4096 * 1024, 1.0f);
  cvt_kernel<<<3072, 256, 0, stream>>>(w_qkv, wqkvb, 3072 * 1024, 1.0f);
  cvt_kernel<<<1024, 256, 0, stream>>>(w_proj, wprojb, 1024 * 1024, 1.0f);
  cvt_kernel<<<4096, 256, 0, stream>>>(attn_bias, biasb, 2048 * 2048, LOG2E);

  gemm_qkv_kernel<<<dim3(24, 32), 256, 0, stream>>>(xb, wqkvb, q_bias, v_bias, scale_mul,
                                                    qb, kb, vb);
  vtrans_kernel<<<256, 256, 0, stream>>>(vb, vtp);
  attn_kernel<<<1024, 128, 0, stream>>>(qb, kb, vtp, biasb, oupb);
  gemm_proj_kernel<<<dim3(8, 32), 256, 0, stream>>>(oupb, wprojb, b_proj, out);
}

// Round 3
// 253.404 us; speedup vs baseline: 1.1450x; 1.0081x over previous
//
#include <hip/hip_runtime.h>
#include <cstdint>
#include <cstddef>
#include <math.h>

typedef __attribute__((ext_vector_type(8))) __bf16 bf16x8;
typedef __attribute__((ext_vector_type(4))) __bf16 bf16x4;
typedef __attribute__((ext_vector_type(4))) float f32x4;

#define AS1 __attribute__((address_space(1)))
#define AS3 __attribute__((address_space(3)))

#define LOG2E 1.4426950408889634f

// async global->LDS, 16B per lane; lds must be wave-uniform base (HW does +lane*16)
__device__ __forceinline__ void gld16(void* lds_uniform, const void* gaddr) {
  __builtin_amdgcn_global_load_lds((const AS1 unsigned int*)gaddr,
                                   (AS3 unsigned int*)lds_uniform, 16, 0, 0);
}

// ---------------------------------------------------------------- fp32->bf16 (with scale)
__global__ void cvt_kernel(const float* __restrict__ src, __bf16* __restrict__ dst, int n,
                           float scale) {
  int i = (blockIdx.x * 256 + threadIdx.x) * 4;
  if (i < n) {
    const float4 v = *(const float4*)(src + i);
    bf16x4 o;
    o[0] = (__bf16)(v.x * scale); o[1] = (__bf16)(v.y * scale);
    o[2] = (__bf16)(v.z * scale); o[3] = (__bf16)(v.w * scale);
    *(bf16x4*)(dst + i) = o;
  }
}

// ---------------------------------------------------------------- QKV GEMM
__global__ __launch_bounds__(256, 2)
void gemm_qkv_kernel(const __bf16* __restrict__ A, const __bf16* __restrict__ B,
                     const float* __restrict__ q_bias, const float* __restrict__ v_bias,
                     const float* __restrict__ scale_mul,
                     __bf16* __restrict__ qb, __bf16* __restrict__ kb, __bf16* __restrict__ vb) {
  __shared__ __attribute__((aligned(16))) __bf16 As[128 * 32];
  __shared__ __attribute__((aligned(16))) __bf16 Bs[128 * 32];
  const int tid = threadIdx.x;
  const int w = tid >> 6, lane = tid & 63;
  const int m0 = blockIdx.y * 128, n0 = blockIdx.x * 128;
  const int wm = (w >> 1) * 64, wn = (w & 1) * 64;
  f32x4 acc[4][4];
#pragma unroll
  for (int i = 0; i < 4; ++i)
#pragma unroll
    for (int j = 0; j < 4; ++j) acc[i][j] = (f32x4)(0.0f);

  const int r_row = lane >> 2;
  const int r_col = (lane & 3) * 16;
  const char* Abase = (const char*)A + (size_t)m0 * 2048;
  const char* Bbase = (const char*)B + (size_t)n0 * 2048;

  for (int kt = 0; kt < 1024; kt += 32) {
#pragma unroll
    for (int s = 0; s < 2; ++s) {
      const int R = w * 2 + s;
      const int row = R * 16 + r_row;
      gld16((char*)As + R * 1024, Abase + (size_t)row * 2048 + kt * 2 + r_col);
      gld16((char*)Bs + R * 1024, Bbase + (size_t)row * 2048 + kt * 2 + r_col);
    }
    __syncthreads();
    bf16x8 af[4], bfr[4];
#pragma unroll
    for (int i = 0; i < 4; ++i) {
      af[i]  = *(const bf16x8*)((const char*)As + (wm + i * 16 + (lane & 15)) * 64 + (lane >> 4) * 16);
      bfr[i] = *(const bf16x8*)((const char*)Bs + (wn + i * 16 + (lane & 15)) * 64 + (lane >> 4) * 16);
    }
#pragma unroll
    for (int mi = 0; mi < 4; ++mi)
#pragma unroll
      for (int ni = 0; ni < 4; ++ni)
        acc[mi][ni] = __builtin_amdgcn_mfma_f32_16x16x32_bf16(af[mi], bfr[ni], acc[mi][ni], 0, 0, 0);
    __syncthreads();
  }

  const int nbase = n0 + wn;
  const int which = nbase >> 10;
  const int h = (nbase >> 6) & 15;
  float smh = 1.0f;
  if (which == 0) smh = __expf(fminf(scale_mul[h], 4.605170185988091f)) * LOG2E;
  float cbias[4];
#pragma unroll
  for (int ni = 0; ni < 4; ++ni) {
    const int n = nbase + ni * 16 + (lane & 15);
    cbias[ni] = (which == 0) ? q_bias[n] : ((which == 2) ? v_bias[n - 2048] : 0.0f);
  }
  __bf16* dst = (which == 0) ? qb : ((which == 1) ? kb : vb);
#pragma unroll
  for (int mi = 0; mi < 4; ++mi) {
#pragma unroll
    for (int j = 0; j < 4; ++j) {
      const int m = m0 + wm + mi * 16 + (lane >> 4) * 4 + j;
      float v[4];
      float ss = 0.0f;
#pragma unroll
      for (int ni = 0; ni < 4; ++ni) { v[ni] = acc[mi][ni][j] + cbias[ni]; ss += v[ni] * v[ni]; }
      ss += __shfl_xor(ss, 1, 64);
      ss += __shfl_xor(ss, 2, 64);
      ss += __shfl_xor(ss, 4, 64);
      ss += __shfl_xor(ss, 8, 64);
      const float sc = (which == 2) ? 1.0f : (rsqrtf(ss) * smh);
      const int b2 = m >> 11, lpos = m & 2047;
      __bf16* drow = dst + ((size_t)((b2 * 16 + h) * 2048 + lpos)) * 64;
#pragma unroll
      for (int ni = 0; ni < 4; ++ni)
        drow[ni * 16 + (lane & 15)] = (__bf16)(v[ni] * sc);
    }
  }
}

// ---------------------------------------------------------------- K rearrange to fragment order
// kb [bh][2048][64] -> ktp tiles of 8KB: tile byte (ks*4096 + key*64 + h2*2) = K[kt*64+key][ks*32+h2]
__global__ __launch_bounds__(256)
void ktrans_kernel(const __bf16* __restrict__ kb, __bf16* __restrict__ ktp) {
  const int u = blockIdx.x * 256 + threadIdx.x;   // 16B unit, 512K total
  const int w_ = u & 511;                         // unit within 8KB tile
  const int tilei = u >> 9;                       // bh*32 + kti
  const int ks = w_ >> 8, key = (w_ >> 2) & 63, h16 = w_ & 3;
  const int bh = tilei >> 5, kti = tilei & 31;
  const uint4 v = *(const uint4*)((const char*)kb +
      ((size_t)(bh * 2048 + kti * 64 + key)) * 128 + ks * 64 + h16 * 16);
  *(uint4*)((char*)ktp + (size_t)u * 16) = v;
}

// ---------------------------------------------------------------- V transpose to tile-slot layout
// vb [bh][2048][64] -> vtp [bh][tile=32][4096]; tile elem (ks*2048 + hd*32 + s32)
//   = V[key][hd], key = tile*64 + (slot&3)*16 + (slot>>2), slot = ks*32+s32.
__global__ __launch_bounds__(256)
void vtrans_kernel(const __bf16* __restrict__ vb, __bf16* __restrict__ vtp) {
  __shared__ __attribute__((aligned(16))) __bf16 Vs[4][64 * 64];
  const int w = threadIdx.x >> 6, lane = threadIdx.x & 63;
  const int idx = blockIdx.x * 4 + w;
  const int bh = idx >> 5, tile = idx & 31;
  const __bf16* src = vb + ((size_t)bh * 2048 + tile * 64) * 64;
#pragma unroll
  for (int s = 0; s < 8; ++s)
    gld16((char*)&Vs[w][0] + s * 1024, (const char*)src + s * 1024 + lane * 16);
  __syncthreads();
  __bf16* outb = vtp + (size_t)idx * 4096;
#pragma unroll
  for (int r = 0; r < 8; ++r) {
    const int o = r * 512 + lane * 8;
    const int hd = (o >> 5) & 63;
    const int sl0 = ((o >> 11) << 5) | (o & 31);
    bf16x8 pk;
#pragma unroll
    for (int i = 0; i < 8; ++i) {
      const int slot = sl0 + i;
      const int key = (slot & 3) * 16 + (slot >> 2);
      pk[i] = Vs[w][key * 64 + hd];
    }
    *(bf16x8*)(outb + o) = pk;
  }
}

// ---------------------------------------------------------------- bias rearrange (fp32 -> bf16*log2e)
// btr[(rb*32 + kti)*64 + lane][32], val idx = mi*16+ni*4+j = bias[rb*32+mi*16+g*4+j][kti*64+ni*16+c]
__global__ __launch_bounds__(64)
void btrans_kernel(const float* __restrict__ bias, __bf16* __restrict__ btr) {
  const int lane = threadIdx.x, c = lane & 15, g = lane >> 4;
  const int kti = blockIdx.x & 31, rb = blockIdx.x >> 5;
  __bf16 out[32];
#pragma unroll
  for (int mi = 0; mi < 2; ++mi)
#pragma unroll
    for (int ni = 0; ni < 4; ++ni)
#pragma unroll
      for (int j = 0; j < 4; ++j)
        out[mi * 16 + ni * 4 + j] = (__bf16)(bias[(size_t)(rb * 32 + mi * 16 + g * 4 + j) * 2048 +
                                                  kti * 64 + ni * 16 + c] * LOG2E);
  __bf16* dst = btr + ((size_t)blockIdx.x * 64 + lane) * 32;
#pragma unroll
  for (int i = 0; i < 4; ++i)
    *(bf16x8*)(dst + i * 8) = *(bf16x8*)(out + i * 8);
}

// ---------------------------------------------------------------- flash attention v3
// 1 wave per block, 32 q-rows, NO barriers; K/V/bias fragments direct from pre-arranged global.
#define LOADK(t, K) {                                                          \
  const char* _b = kp + (size_t)(t) * 8192 + laneoff;                          \
  _Pragma("unroll")                                                            \
  for (int f = 0; f < 8; ++f)                                                  \
    K[f] = *(const bf16x8*)(_b + (f & 1) * 4096 + (f >> 1) * 1024);            \
}
#define LOADBIAS(t, BB) {                                                      \
  const char* _b = bp + ((size_t)(t) * 64 + lane) * 64;                        \
  _Pragma("unroll")                                                            \
  for (int i = 0; i < 4; ++i) BB[i] = *(const bf16x8*)(_b + i * 16);           \
}
#define COMPUTE(t, K, BB) {                                                    \
  bf16x8 vf[8];                                                                \
  {                                                                            \
    const char* _b = vp + (size_t)(t) * 8192 + laneoff;                        \
    _Pragma("unroll")                                                          \
    for (int f = 0; f < 8; ++f)                                                \
      vf[f] = *(const bf16x8*)(_b + (f & 1) * 4096 + (f >> 1) * 1024);         \
  }                                                                            \
  f32x4 sacc[2][4];                                                            \
  _Pragma("unroll")                                                            \
  for (int mi = 0; mi < 2; ++mi)                                               \
    _Pragma("unroll")                                                          \
    for (int ni = 0; ni < 4; ++ni) {                                           \
      f32x4 s_ = (f32x4)(0.0f);                                                \
      s_ = __builtin_amdgcn_mfma_f32_16x16x32_bf16(qf[mi][0], K[ni * 2 + 0], s_, 0, 0, 0); \
      s_ = __builtin_amdgcn_mfma_f32_16x16x32_bf16(qf[mi][1], K[ni * 2 + 1], s_, 0, 0, 0); \
      sacc[mi][ni] = s_;                                                       \
    }                                                                          \
  _Pragma("unroll")                                                            \
  for (int mi = 0; mi < 2; ++mi)                                               \
    _Pragma("unroll")                                                          \
    for (int j = 0; j < 4; ++j) {                                              \
      const float p0 = __builtin_amdgcn_exp2f(sacc[mi][0][j] + (float)BB[(mi * 16 + 0 + j) >> 3][(mi * 16 + 0 + j) & 7]);  \
      const float p1 = __builtin_amdgcn_exp2f(sacc[mi][1][j] + (float)BB[(mi * 16 + 4 + j) >> 3][(mi * 16 + 4 + j) & 7]);  \
      const float p2 = __builtin_amdgcn_exp2f(sacc[mi][2][j] + (float)BB[(mi * 16 + 8 + j) >> 3][(mi * 16 + 8 + j) & 7]);  \
      const float p3 = __builtin_amdgcn_exp2f(sacc[mi][3][j] + (float)BB[(mi * 16 + 12 + j) >> 3][(mi * 16 + 12 + j) & 7]);\
      lsum[mi][j] += (p0 + p1) + (p2 + p3);                                    \
      bf16x4 pk;                                                               \
      pk[0] = (__bf16)p0; pk[1] = (__bf16)p1; pk[2] = (__bf16)p2; pk[3] = (__bf16)p3; \
      *(bf16x4*)&Ps[c >> 3][mi * 16 + g * 4 + j][(c & 7) * 4] = pk;            \
    }                                                                          \
  bf16x8 pf[2][2];                                                             \
  _Pragma("unroll")                                                            \
  for (int mi = 0; mi < 2; ++mi)                                               \
    _Pragma("unroll")                                                          \
    for (int ks = 0; ks < 2; ++ks)                                             \
      pf[mi][ks] = *(const bf16x8*)&Ps[ks][mi * 16 + c][g * 8];                \
  _Pragma("unroll")                                                            \
  for (int mi = 0; mi < 2; ++mi)                                               \
    _Pragma("unroll")                                                          \
    for (int ni = 0; ni < 4; ++ni) {                                           \
      oacc[mi][ni] = __builtin_amdgcn_mfma_f32_16x16x32_bf16(pf[mi][0], vf[ni * 2 + 0], oacc[mi][ni], 0, 0, 0); \
      oacc[mi][ni] = __builtin_amdgcn_mfma_f32_16x16x32_bf16(pf[mi][1], vf[ni * 2 + 1], oacc[mi][ni], 0, 0, 0); \
    }                                                                          \
}

__global__ __launch_bounds__(64, 2)
void attn_kernel(const __bf16* __restrict__ qb, const __bf16* __restrict__ ktp,
                 const __bf16* __restrict__ vtp, const __bf16* __restrict__ btr,
                 __bf16* __restrict__ oupb) {
  __shared__ __attribute__((aligned(16))) __bf16 Ps[2][32][32];  // 4KB, wave-private
  const int lane = threadIdx.x;
  const int c = lane & 15, g = lane >> 4;
  const int bh = blockIdx.x & 31, qt = blockIdx.x >> 5;   // qt in [0,64)
  const int b2 = bh >> 4, h = bh & 15;
  const __bf16* qh = qb + (size_t)bh * (2048 * 64);
  const char* kp = (const char*)ktp + (size_t)bh * (32 * 8192);
  const char* vp = (const char*)vtp + (size_t)bh * (32 * 8192);
  const char* bp = (const char*)btr + (size_t)qt * (32 * 64 * 64);
  const int q0 = qt * 32;
  const int laneoff = c * 64 + g * 16;

  bf16x8 qf[2][2];
#pragma unroll
  for (int mi = 0; mi < 2; ++mi)
#pragma unroll
    for (int ks = 0; ks < 2; ++ks)
      qf[mi][ks] = *(const bf16x8*)(qh + (size_t)(q0 + mi * 16 + c) * 64 + ks * 32 + g * 8);

  f32x4 oacc[2][4];
  float lsum[2][4];
#pragma unroll
  for (int mi = 0; mi < 2; ++mi)
#pragma unroll
    for (int ni = 0; ni < 4; ++ni) oacc[mi][ni] = (f32x4)(0.0f);
#pragma unroll
  for (int mi = 0; mi < 2; ++mi)
#pragma unroll
    for (int j = 0; j < 4; ++j) lsum[mi][j] = 0.0f;

  bf16x8 kA[8], kB[8], bA[4], bB[4];
  LOADK(0, kA); LOADBIAS(0, bA);
  for (int t = 0; t < 32; t += 2) {
    LOADK(t + 1, kB); LOADBIAS(t + 1, bB);
    COMPUTE(t, kA, bA);
    if (t + 2 < 32) { LOADK(t + 2, kA); LOADBIAS(t + 2, bA); }
    COMPUTE(t + 1, kB, bB);
  }

#pragma unroll
  for (int mi = 0; mi < 2; ++mi)
#pragma unroll
    for (int j = 0; j < 4; ++j) {
      float l = lsum[mi][j];
      l += __shfl_xor(l, 1, 64);
      l += __shfl_xor(l, 2, 64);
      l += __shfl_xor(l, 4, 64);
      l += __shfl_xor(l, 8, 64);
      const float inv = 1.0f / l;
      const int qrow = q0 + mi * 16 + g * 4 + j;
      __bf16* orow = oupb + ((size_t)(b2 * 2048 + qrow) * 16 + h) * 64;
#pragma unroll
      for (int ni = 0; ni < 4; ++ni)
        orow[ni * 16 + c] = (__bf16)(oacc[mi][ni][j] * inv);
    }
}

// ---------------------------------------------------------------- proj GEMM
__global__ __launch_bounds__(256, 2)
void gemm_proj_kernel(const __bf16* __restrict__ A, const __bf16* __restrict__ B,
                      const float* __restrict__ b_proj, float* __restrict__ out) {
  __shared__ __attribute__((aligned(16))) __bf16 As[128 * 32];
  __shared__ __attribute__((aligned(16))) __bf16 Bs[128 * 32];
  const int tid = threadIdx.x;
  const int w = tid >> 6, lane = tid & 63;
  const int m0 = blockIdx.y * 128, n0 = blockIdx.x * 128;
  const int wm = (w >> 1) * 64, wn = (w & 1) * 64;
  f32x4 acc[4][4];
#pragma unroll
  for (int i = 0; i < 4; ++i)
#pragma unroll
    for (int j = 0; j < 4; ++j) acc[i][j] = (f32x4)(0.0f);

  const int r_row = lane >> 2;
  const int r_col = (lane & 3) * 16;
  const char* Abase = (const char*)A + (size_t)m0 * 2048;
  const char* Bbase = (const char*)B + (size_t)n0 * 2048;

  for (int kt = 0; kt < 1024; kt += 32) {
#pragma unroll
    for (int s = 0; s < 2; ++s) {
      const int R = w * 2 + s;
      const int row = R * 16 + r_row;
      gld16((char*)As + R * 1024, Abase + (size_t)row * 2048 + kt * 2 + r_col);
      gld16((char*)Bs + R * 1024, Bbase + (size_t)row * 2048 + kt * 2 + r_col);
    }
    __syncthreads();
    bf16x8 af[4], bfr[4];
#pragma unroll
    for (int i = 0; i < 4; ++i) {
      af[i]  = *(const bf16x8*)((const char*)As + (wm + i * 16 + (lane & 15)) * 64 + (lane >> 4) * 16);
      bfr[i] = *(const bf16x8*)((const char*)Bs + (wn + i * 16 + (lane & 15)) * 64 + (lane >> 4) * 16);
    }
#pragma unroll
    for (int mi = 0; mi < 4; ++mi)
#pragma unroll
      for (int ni = 0; ni < 4; ++ni)
        acc[mi][ni] = __builtin_amdgcn_mfma_f32_16x16x32_bf16(af[mi], bfr[ni], acc[mi][ni], 0, 0, 0);
    __syncthreads();
  }

  float cbias[4];
#pragma unroll
  for (int ni = 0; ni < 4; ++ni) cbias[ni] = b_proj[n0 + wn + ni * 16 + (lane & 15)];
#pragma unroll
  for (int mi = 0; mi < 4; ++mi)
#pragma unroll
    for (int j = 0; j < 4; ++j) {
      const int m = m0 + wm + mi * 16 + (lane >> 4) * 4 + j;
      float* orow = out + (size_t)m * 1024 + n0 + wn;
#pragma unroll
      for (int ni = 0; ni < 4; ++ni)
        orow[ni * 16 + (lane & 15)] = acc[mi][ni][j] + cbias[ni];
    }
}

// ---------------------------------------------------------------- launch
extern "C" void kernel_launch(void* const* d_in, const int* in_sizes, int n_in,
                              void* d_out, int out_size, void* d_ws, size_t ws_size,
                              hipStream_t stream) {
  const float* x         = (const float*)d_in[0];
  const float* attn_bias = (const float*)d_in[1];
  const float* w_qkv     = (const float*)d_in[2];
  const float* q_bias    = (const float*)d_in[3];
  const float* v_bias    = (const float*)d_in[4];
  const float* scale_mul = (const float*)d_in[5];
  const float* w_proj    = (const float*)d_in[6];
  const float* b_proj    = (const float*)d_in[7];
  float* out = (float*)d_out;

  __bf16* xb     = (__bf16*)d_ws;                 // 4096*1024
  __bf16* wqkvb  = xb + 4096 * 1024;              // 3072*1024
  __bf16* wprojb = wqkvb + 3072 * 1024;           // 1024*1024
  __bf16* qb     = wprojb + 1024 * 1024;          // 2*16*2048*64 (q scaled by log2e)
  __bf16* kb     = qb + 4194304;
  __bf16* vb     = kb + 4194304;
  __bf16* oupb   = vb + 4194304;                  // 4096*1024
  __bf16* vtp    = oupb + 4194304;                // V fragment-order
  __bf16* ktp    = vtp + 4194304;                 // K fragment-order
  __bf16* btr    = ktp + 4194304;                 // bias per-lane order (scaled by log2e)

  btrans_kernel<<<2048, 64, 0, stream>>>(attn_bias, btr);
  cvt_kernel<<<4096, 256, 0, stream>>>(x, xb, 4096 * 1024, 1.0f);
  cvt_kernel<<<3072, 256, 0, stream>>>(w_qkv, wqkvb, 3072 * 1024, 1.0f);
  cvt_kernel<<<1024, 256, 0, stream>>>(w_proj, wprojb, 1024 * 1024, 1.0f);

  gemm_qkv_kernel<<<dim3(24, 32), 256, 0, stream>>>(xb, wqkvb, q_bias, v_bias, scale_mul,
                                                    qb, kb, vb);
  ktrans_kernel<<<2048, 256, 0, stream>>>(kb, ktp);
  vtrans_kernel<<<256, 256, 0, stream>>>(vb, vtp);
  attn_kernel<<<2048, 64, 0, stream>>>(qb, ktp, vtp, btr, oupb);
  gemm_proj_kernel<<<dim3(8, 32), 256, 0, stream>>>(oupb, wprojb, b_proj, out);
}